// Round 17
// baseline (186.622 us; speedup 1.0000x reference)
//
#include <hip/hip_runtime.h>

// ---------------------------------------------------------------------------
// SelfAttention: x[4,2048,1024] f32, w_qkv[1024,3072] f32, w_out[1024,1024] f32
//   qkv = x @ w_qkv ; 16-head attention (scale = 1024^-0.5 = 1/32) ; out @ w_out
// f32 buffers; compute in bf16 MFMA (fp32 accum). Attention uses max-free
// softmax (|S|<=72 deterministically, softmax shift-invariant) with log2(e)/32
// folded into W_qkv's Q-columns so softmax = raw v_exp_f32 (exp2).
// GEMMs: 128^2 tile, BK=32, global_load_lds w=16, 3-buffer counted-vmcnt
// rotation (T4): stage 2 ahead, vmcnt(4) + raw s_barrier per K-step, no
// vmcnt(0) drain in the main loop. Epilogue: per-wave LDS transpose bounce ->
// packed dwordx4 C-stores (was 64 scalar stores/thread at 25-50% coalescing).
// Attention: same T4 pattern; 32x32x16 MFMA, swapped QK^T, P in registers
// (permlane32_swap), 64 q/wave (2 q-sets), 4 waves/block.
// ---------------------------------------------------------------------------

typedef __bf16 bf16x8 __attribute__((ext_vector_type(8)));
typedef __bf16 bf16x4 __attribute__((ext_vector_type(4)));
typedef __bf16 bf16x2 __attribute__((ext_vector_type(2)));
typedef float f32x4 __attribute__((ext_vector_type(4)));
typedef float f32x2 __attribute__((ext_vector_type(2)));
typedef float f32x16 __attribute__((ext_vector_type(16)));
typedef unsigned short ushort8 __attribute__((ext_vector_type(8)));

#define MFMA16(a, b, c) __builtin_amdgcn_mfma_f32_16x16x32_bf16((a), (b), (c), 0, 0, 0)
#define MFMA32(a, b, c) __builtin_amdgcn_mfma_f32_32x32x16_bf16((a), (b), (c), 0, 0, 0)

__device__ __forceinline__ unsigned short f2bf(float f) {
  unsigned int u = __float_as_uint(f);
  u = (u + 0x7FFFu + ((u >> 16) & 1u)) >> 16;  // RNE
  return (unsigned short)u;
}

// Raw v_exp_f32 (exp2). Inputs bounded (|x| <= ~105): no libm guard needed.
__device__ __forceinline__ float fast_exp2(float x) {
#if __has_builtin(__builtin_amdgcn_exp2f)
  return __builtin_amdgcn_exp2f(x);
#else
  float r;
  asm("v_exp_f32 %0, %1" : "=v"(r) : "v"(x));
  return r;
#endif
}

// async global->LDS, 16B per lane. lds dest: wave-uniform base, HW adds lane*16.
__device__ __forceinline__ void gload_lds16(const unsigned short* g, unsigned short* l) {
  __builtin_amdgcn_global_load_lds(
      (const __attribute__((address_space(1))) unsigned int*)g,
      (__attribute__((address_space(3))) unsigned int*)l, 16, 0, 0);
}

// Exchange lane-halves: x[lane<32]=a, x[lane>=32]=b@(lane-32);
//                       y[lane<32]=a@(lane+32), y[lane>=32]=b.
__device__ __forceinline__ void half_swap(unsigned int a, unsigned int b,
                                          unsigned int& x, unsigned int& y,
                                          bool H) {
#if __has_builtin(__builtin_amdgcn_permlane32_swap)
  auto r = __builtin_amdgcn_permlane32_swap(a, b, false, false);
  x = (unsigned int)r[0];
  y = (unsigned int)r[1];
#else
  unsigned int oa = (unsigned int)__shfl_xor((int)a, 32);
  unsigned int ob = (unsigned int)__shfl_xor((int)b, 32);
  x = H ? ob : a;
  y = H ? b : oa;
#endif
}

// ---------------------------------------------------------------------------
// Fused prep: blocks [0,4096): x f32->bf16 (8/thread, 16B stores)
//             blocks [4096,7168): transpose w_qkv -> WqkvT (Q cols pre-scaled)
//             blocks [7168,8192): transpose w_out -> WoutT
// ---------------------------------------------------------------------------
__global__ __launch_bounds__(256) void prep_kernel(
    const float* __restrict__ x, unsigned short* __restrict__ xb,
    const float* __restrict__ wqkv, unsigned short* __restrict__ WqkvT,
    const float* __restrict__ wout, unsigned short* __restrict__ WoutT) {
  const int bid = blockIdx.x;
  const int tid = threadIdx.x;
  if (bid < 4096) {
    int i = (bid * 256 + tid) * 8;
    float4 a = *(const float4*)&x[i];
    float4 b = *(const float4*)&x[i + 4];
    ushort8 o = {f2bf(a.x), f2bf(a.y), f2bf(a.z), f2bf(a.w),
                 f2bf(b.x), f2bf(b.y), f2bf(b.z), f2bf(b.w)};
    *(ushort8*)&xb[i] = o;
    return;
  }
  __shared__ float t[32][33];
  const float* in;
  unsigned short* out;
  int C, scale_limit, c0, r0;
  if (bid < 4096 + 3072) {
    int tj = bid - 4096;
    in = wqkv; out = WqkvT; C = 3072; scale_limit = 1024;
    c0 = (tj % 96) * 32; r0 = (tj / 96) * 32;
  } else {
    int tj = bid - 7168;
    in = wout; out = WoutT; C = 1024; scale_limit = 0;
    c0 = (tj & 31) * 32; r0 = (tj >> 5) * 32;
  }
  const float kQScale = 0.045084220027780106f;  // log2(e) / 32
#pragma unroll
  for (int i = 0; i < 4; ++i) {
    int e = tid + i * 256;
    int r = e >> 5, c = e & 31;
    t[r][c] = in[(size_t)(r0 + r) * C + c0 + c];
  }
  __syncthreads();
#pragma unroll
  for (int i = 0; i < 4; ++i) {
    int e = tid + i * 256;
    int r = e >> 5, c = e & 31;
    float v = t[c][r];
    if (c0 + r < scale_limit) v *= kQScale;
    out[(size_t)(c0 + r) * 1024 + r0 + c] = f2bf(v);
  }
}

// ---------------------------------------------------------------------------
// GEMM: C[M][N] = A[M][K] * Bt[N][K]^T (bf16 in, fp32 accum). 128x128 tile,
// BK=32, linear LDS, global_load_lds w=16, 3-buffer counted-vmcnt rotation.
// Epilogue: __syncthreads once, then per-wave LDS bounce (scalar ds_write at
// padded stride -> packed b128 read -> dwordx4 global stores, 128B/row per
// 4 lanes). MODE 0: bf16 C. MODE 1: f32 C. MODE 2 (QKV): V-third -> VT.
// ---------------------------------------------------------------------------
template <int MODE>
__global__ __launch_bounds__(256) void gemm_bt(
    const unsigned short* __restrict__ A, const unsigned short* __restrict__ Bt,
    void* __restrict__ Cv, unsigned short* __restrict__ VT,
    int M, int N, int K) {
  __shared__ unsigned short As[3 * 4096];  // [buf][128 rows][32 cols]
  __shared__ unsigned short Bs[3 * 4096];
  const int tid = threadIdx.x;
  const int wave = tid >> 6, lane = tid & 63;
  const int g = lane >> 4, ln = lane & 15;
  const int wm = wave >> 1, wn = wave & 1;
  const long bm = (long)blockIdx.y * 128;
  const long bn = (long)blockIdx.x * 128;

  f32x4 acc[4][4];
#pragma unroll
  for (int i = 0; i < 4; ++i)
#pragma unroll
    for (int j = 0; j < 4; ++j) acc[i][j] = (f32x4){0.f, 0.f, 0.f, 0.f};

  const int srow = wave * 32 + (lane >> 2);
  const int scol = (lane & 3) * 8;
  const unsigned short* gA0 = A + (bm + srow) * (long)K + scol;
  const unsigned short* gA1 = gA0 + 16 * (long)K;
  const unsigned short* gB0 = Bt + (bn + srow) * (long)K + scol;
  const unsigned short* gB1 = gB0 + 16 * (long)K;

  auto STAGE = [&](int buf, int k0) {
    unsigned short* lA = &As[buf * 4096 + wave * 1024];
    unsigned short* lB = &Bs[buf * 4096 + wave * 1024];
    gload_lds16(gA0 + k0, lA);
    gload_lds16(gA1 + k0, lA + 512);
    gload_lds16(gB0 + k0, lB);
    gload_lds16(gB1 + k0, lB + 512);
  };

  STAGE(0, 0);
  STAGE(1, 32);

  int bidx = 0;
  for (int k0 = 0; k0 < K; k0 += 32) {
    if (k0 + 32 < K)
      asm volatile("s_waitcnt vmcnt(4)" ::: "memory");
    else
      asm volatile("s_waitcnt vmcnt(0)" ::: "memory");
    __builtin_amdgcn_s_barrier();       // raw: tile j+1 loads stay in flight
    __builtin_amdgcn_sched_barrier(0);  // no hoisting above the barrier
    if (k0 + 64 < K) {
      int nb = bidx + 2; if (nb >= 3) nb -= 3;
      STAGE(nb, k0 + 64);               // overwrites tile j-1's buffer (safe)
    }

    bf16x8 af[4], bfr[4];
#pragma unroll
    for (int i = 0; i < 4; ++i) {
      af[i]  = *(const bf16x8*)&As[bidx * 4096 + (wm * 64 + i * 16 + ln) * 32 + g * 8];
      bfr[i] = *(const bf16x8*)&Bs[bidx * 4096 + (wn * 64 + i * 16 + ln) * 32 + g * 8];
    }
    __builtin_amdgcn_s_setprio(1);
#pragma unroll
    for (int i = 0; i < 4; ++i)
#pragma unroll
      for (int j = 0; j < 4; ++j)
        acc[i][j] = MFMA16(af[i], bfr[j], acc[i][j]);
    __builtin_amdgcn_s_setprio(0);

    bidx = (bidx == 2) ? 0 : bidx + 1;
  }

  const long crow = bm + wm * 64, ccol = bn + wn * 64;
  if (MODE == 2 && bn >= 2048) {
    // V block: write VT[bh][dh][t] only (qkv's V third is never read).
#pragma unroll
    for (int i = 0; i < 4; ++i)
#pragma unroll
      for (int j = 0; j < 4; ++j) {
        int nv = (int)(ccol + j * 16 + ln) - 2048;  // 0..1023
        int h = nv >> 6, dh = nv & 63;
        long tg = crow + i * 16 + g * 4;            // t of acc[..][0]
        int b = (int)(tg >> 11), tl = (int)(tg & 2047);
        size_t idx = (size_t)(b * 16 + h) * 131072 + (size_t)dh * 2048 + tl;
        bf16x4 o = {(__bf16)acc[i][j][0], (__bf16)acc[i][j][1],
                    (__bf16)acc[i][j][2], (__bf16)acc[i][j][3]};
        *(bf16x4*)&VT[idx] = o;
      }
  } else {
    // Packed epilogue: bounce each 16x64 sub-tile through (now-dead) staging
    // LDS so stores become full 128B-per-4-lane dwordx4 lines.
    __syncthreads();  // all K-loop LDS reads done; safe to reuse As
    const int erow = lane >> 2, ec = (lane & 3) * 16;
    if (MODE == 1) {
      float* lf = ((float*)As) + wave * 1088;  // 16 rows x stride 68 (16B-aligned)
      float* Cf = (float*)Cv;
#pragma unroll
      for (int i = 0; i < 4; ++i) {
#pragma unroll
        for (int j = 0; j < 4; ++j)
#pragma unroll
          for (int r = 0; r < 4; ++r)
            lf[(g * 4 + r) * 68 + j * 16 + ln] = acc[i][j][r];
        // wave-private region; per-wave LDS ops are in-order (WAR safe)
#pragma unroll
        for (int c = 0; c < 4; ++c) {
          f32x4 v = *(const f32x4*)&lf[erow * 68 + ec + c * 4];
          *(f32x4*)&Cf[(crow + i * 16 + erow) * (long)N + ccol + ec + c * 4] = v;
        }
      }
    } else {
      unsigned short* lb = ((unsigned short*)As) + wave * 1152;  // stride 72
      unsigned short* Cb = (unsigned short*)Cv;
#pragma unroll
      for (int i = 0; i < 4; ++i) {
#pragma unroll
        for (int j = 0; j < 4; ++j)
#pragma unroll
          for (int r = 0; r < 4; ++r)
            lb[(g * 4 + r) * 72 + j * 16 + ln] = f2bf(acc[i][j][r]);
#pragma unroll
        for (int c = 0; c < 2; ++c) {
          ushort8 v = *(const ushort8*)&lb[erow * 72 + ec + c * 8];
          *(ushort8*)&Cb[(crow + i * 16 + erow) * (long)N + ccol + ec + c * 8] = v;
        }
      }
    }
  }
}

// ---------------------------------------------------------------------------
// Flash attention, 32x32x16 MFMA, swapped-operand, max-free softmax, P in regs.
// Block = one (b,h) x 256 q-rows; 4 waves x 64 q each (two 32-q sets A,B).
// 3-buffer K/V rotation, staged 2 tiles ahead; per tile:
//   s_waitcnt vmcnt(4) -> raw s_barrier -> STAGE(j+2) -> compute tile j.
// No ds_writes exist (P in regs) -> raw barrier needs no lgkm drain.
// ---------------------------------------------------------------------------
__global__ __launch_bounds__(256, 2) void attn_kernel(
    const unsigned short* __restrict__ qkv, const unsigned short* __restrict__ VT,
    unsigned short* __restrict__ attn_out) {
  __shared__ unsigned short Ks[3][64][64];  // [buf][key][dh], swizzled content
  __shared__ unsigned short Vs[3][64][64];  // [buf][dh][key], swizzled content

  const int tid = threadIdx.x;
  const int wave = tid >> 6, lane = tid & 63;
  const int l31 = lane & 31, hb = lane >> 5;

  // XCD-chunked bijective swizzle: each XCD owns 64 consecutive wg = 8 bh
  // (K/V working set 8*512KB = 4MB = L2-resident).
  const int wg = (blockIdx.x & 7) * 64 + (blockIdx.x >> 3);
  const int bh = wg >> 3, qc = wg & 7;
  const int b = bh >> 4, head = bh & 15;
  const int q0 = qc * 256 + wave * 64;  // this wave's 64 q-rows (A: +0, B: +32)

  // Q B-frags, two sets: qf*[t]: n=q, k(dh) = 16t + 8hb + i. W_q pre-scaled.
  bf16x8 qfA[4], qfB[4];
  {
    size_t baseA = (size_t)(b * 2048 + q0 + l31) * 3072 + head * 64 + 8 * hb;
    size_t baseB = baseA + (size_t)32 * 3072;
    qfA[0] = *(const bf16x8*)&qkv[baseA];
    qfA[1] = *(const bf16x8*)&qkv[baseA + 16];
    qfA[2] = *(const bf16x8*)&qkv[baseA + 32];
    qfA[3] = *(const bf16x8*)&qkv[baseA + 48];
    qfB[0] = *(const bf16x8*)&qkv[baseB];
    qfB[1] = *(const bf16x8*)&qkv[baseB + 16];
    qfB[2] = *(const bf16x8*)&qkv[baseB + 32];
    qfB[3] = *(const bf16x8*)&qkv[baseB + 48];
  }

  f32x16 oaccA[2], oaccB[2];
#pragma unroll
  for (int i = 0; i < 16; ++i) {
    oaccA[0][i] = 0.f; oaccA[1][i] = 0.f;
    oaccB[0][i] = 0.f; oaccB[1][i] = 0.f;
  }
  f32x2 lsA = {0.f, 0.f}, lsB = {0.f, 0.f};

  // Staging: LDS linear (gload_lds HW layout); global SOURCE pre-swizzled
  // (chunk sc ^ (srow&7)) so reading LDS[row][c ^ (row&7)] = logical col c.
  const int srow = tid >> 3;                     // 0..31
  const int sc = tid & 7;
  const int swz = (sc ^ (srow & 7)) * 8;         // swizzled chunk (elems)
  const unsigned short* gK =
      qkv + (size_t)b * 2048 * 3072 + 1024 + head * 64 + (size_t)srow * 3072 + swz;
  const unsigned short* gV = VT + (size_t)bh * 131072 + (size_t)srow * 2048 + swz;
  const int wrow = wave * 8;  // wave-uniform LDS row base for staging

  auto STAGE = [&](int buf, int j) {
    gload_lds16(gK + (size_t)j * 3072,        &Ks[buf][wrow][0]);
    gload_lds16(gK + (size_t)(j + 32) * 3072, &Ks[buf][wrow + 32][0]);
    gload_lds16(gV + j,                       &Vs[buf][wrow][0]);
    gload_lds16(gV + 32 * 2048 + j,           &Vs[buf][wrow + 32][0]);
  };

  const int myx = l31 & 7;  // XOR key for frag reads
  const bool H = (hb != 0);

  // prologue: stage tiles 0 and 1 into bufs 0 and 1
  STAGE(0, 0);
  STAGE(1, 64);

  int idx = 0;
  for (int j0 = 0; j0 < 2048; j0 += 64) {
    // Tile j resident when all but the newest 4 loads (tile j+1) are done.
    if (j0 + 64 < 2048)
      asm volatile("s_waitcnt vmcnt(4)" ::: "memory");
    else
      asm volatile("s_waitcnt vmcnt(0)" ::: "memory");
    __builtin_amdgcn_s_barrier();      // raw: loads for j+1 stay in flight
    __builtin_amdgcn_sched_barrier(0); // pin: no hoisting above the barrier
    if (j0 + 128 < 2048) {
      int nb = idx + 2; if (nb >= 3) nb -= 3;
      STAGE(nb, j0 + 128);             // overwrites tile j-1's buffer (safe)
    }

#pragma unroll
    for (int kt = 0; kt < 2; ++kt) {
      // S^T over 32 keys (this kt) x 64 q: one kf read feeds both q-sets.
      f32x16 saA, saB;
#pragma unroll
      for (int i = 0; i < 16; ++i) { saA[i] = 0.f; saB[i] = 0.f; }
      __builtin_amdgcn_s_setprio(1);
#pragma unroll
      for (int t = 0; t < 4; ++t) {
        bf16x8 kf = *(const bf16x8*)&Ks[idx][kt * 32 + l31][((2 * t + hb) ^ myx) * 8];
        saA = MFMA32(kf, qfA[t], saA);
        saB = MFMA32(kf, qfB[t], saB);
      }
      __builtin_amdgcn_s_setprio(0);

      // P = exp2(S); pack reg-pairs to bf16x2; lane-local pk_add lsum.
      unsigned int pkwA[8], pkwB[8];
#pragma unroll
      for (int j = 0; j < 8; ++j) {
        float a0 = fast_exp2(saA[2 * j]);
        float a1 = fast_exp2(saA[2 * j + 1]);
        lsA += (f32x2){a0, a1};
        bf16x2 av = {(__bf16)a0, (__bf16)a1};
        pkwA[j] = __builtin_bit_cast(unsigned int, av);
        float b0 = fast_exp2(saB[2 * j]);
        float b1 = fast_exp2(saB[2 * j + 1]);
        lsB += (f32x2){b0, b1};
        bf16x2 bv = {(__bf16)b0, (__bf16)b1};
        pkwB[j] = __builtin_bit_cast(unsigned int, bv);
      }

      // Reassemble PV B-frags via lane-half swaps (element i -> key 16s+8hb+i).
      union { unsigned int u[4]; bf16x8 v; } pfA0, pfA1, pfB0, pfB1;
      half_swap(pkwA[0], pkwA[2], pfA0.u[0], pfA0.u[2], H);
      half_swap(pkwA[1], pkwA[3], pfA0.u[1], pfA0.u[3], H);
      half_swap(pkwA[4], pkwA[6], pfA1.u[0], pfA1.u[2], H);
      half_swap(pkwA[5], pkwA[7], pfA1.u[1], pfA1.u[3], H);
      half_swap(pkwB[0], pkwB[2], pfB0.u[0], pfB0.u[2], H);
      half_swap(pkwB[1], pkwB[3], pfB0.u[1], pfB0.u[3], H);
      half_swap(pkwB[4], pkwB[6], pfB1.u[0], pfB1.u[2], H);
      half_swap(pkwB[5], pkwB[7], pfB1.u[1], pfB1.u[3], H);

      // O^T += V^T * P^T: one vf pair read feeds both q-sets.
      __builtin_amdgcn_s_setprio(1);
#pragma unroll
      for (int mt = 0; mt < 2; ++mt) {
        bf16x8 vf0 = *(const bf16x8*)&Vs[idx][mt * 32 + l31][((4 * kt + hb) ^ myx) * 8];
        bf16x8 vf1 = *(const bf16x8*)&Vs[idx][mt * 32 + l31][((4 * kt + 2 + hb) ^ myx) * 8];
        oaccA[mt] = MFMA32(vf0, pfA0.v, oaccA[mt]);
        oaccA[mt] = MFMA32(vf1, pfA1.v, oaccA[mt]);
        oaccB[mt] = MFMA32(vf0, pfB0.v, oaccB[mt]);
        oaccB[mt] = MFMA32(vf1, pfB1.v, oaccB[mt]);
      }
      __builtin_amdgcn_s_setprio(0);
    }

    idx = (idx == 2) ? 0 : idx + 1;
  }

  // Epilogue per set: halves hold disjoint key sets for the same q.
  {
    float l = lsA.x + lsA.y;
    l += __shfl_xor(l, 32);
    float inv = 1.0f / l;
    size_t row = (size_t)(b * 2048 + q0 + l31) * 1024 + head * 64;
#pragma unroll
    for (int mt = 0; mt < 2; ++mt)
#pragma unroll
      for (int rq = 0; rq < 4; ++rq) {
        bf16x4 o = {(__bf16)(oaccA[mt][4 * rq + 0] * inv),
                    (__bf16)(oaccA[mt][4 * rq + 1] * inv),
                    (__bf16)(oaccA[mt][4 * rq + 2] * inv),
                    (__bf16)(oaccA[mt][4 * rq + 3] * inv)};
        *(bf16x4*)&attn_out[row + mt * 32 + 8 * rq + 4 * hb] = o;
      }
  }
  {
    float l = lsB.x + lsB.y;
    l += __shfl_xor(l, 32);
    float inv = 1.0f / l;
    size_t row = (size_t)(b * 2048 + q0 + 32 + l31) * 1024 + head * 64;
#pragma unroll
    for (int mt = 0; mt < 2; ++mt)
#pragma unroll
      for (int rq = 0; rq < 4; ++rq) {
        bf16x4 o = {(__bf16)(oaccB[mt][4 * rq + 0] * inv),
                    (__bf16)(oaccB[mt][4 * rq + 1] * inv),
                    (__bf16)(oaccB[mt][4 * rq + 2] * inv),
                    (__bf16)(oaccB[mt][4 * rq + 3] * inv)};
        *(bf16x4*)&attn_out[row + mt * 32 + 8 * rq + 4 * hb] = o;
      }
  }
}

// ---------------------------------------------------------------------------
extern "C" void kernel_launch(void* const* d_in, const int* in_sizes, int n_in,
                              void* d_out, int out_size, void* d_ws, size_t ws_size,
                              hipStream_t stream) {
  (void)in_sizes; (void)n_in; (void)out_size; (void)ws_size;
  const float* x_f     = (const float*)d_in[0];
  const float* w_qkv_f = (const float*)d_in[1];
  const float* w_out_f = (const float*)d_in[2];
  float* out = (float*)d_out;

  char* ws = (char*)d_ws;
  unsigned short* qkv   = (unsigned short*)(ws);                 // 50331648 B
  unsigned short* attn  = (unsigned short*)(ws + 50331648);      // 16777216 B
  unsigned short* VT    = (unsigned short*)(ws + 67108864);      // 16777216 B
  unsigned short* WqkvT = (unsigned short*)(ws + 83886080);      // 6291456 B
  unsigned short* WoutT = (unsigned short*)(ws + 90177536);      // 2097152 B
  unsigned short* xb    = (unsigned short*)(ws + 92274688);      // 16777216 B

  prep_kernel<<<8192, 256, 0, stream>>>(x_f, xb, w_qkv_f, WqkvT, w_out_f, WoutT);
  gemm_bt<2><<<dim3(24, 64), 256, 0, stream>>>(xb, WqkvT, qkv, VT, 8192, 3072, 1024);
  attn_kernel<<<512, 256, 0, stream>>>(qkv, VT, attn);
  gemm_bt<1><<<dim3(8, 64), 256, 0, stream>>>(attn, WoutT, out, nullptr, 8192, 1024, 1024);
}

// Round 18
// 178.887 us; speedup vs baseline: 1.0432x; 1.0432x over previous
//
#include <hip/hip_runtime.h>

// ---------------------------------------------------------------------------
// SelfAttention: x[4,2048,1024] f32, w_qkv[1024,3072] f32, w_out[1024,1024] f32
//   qkv = x @ w_qkv ; 16-head attention (scale = 1024^-0.5 = 1/32) ; out @ w_out
// f32 buffers; compute in bf16 MFMA (fp32 accum). Attention uses max-free
// softmax (|S|<=72 deterministically, softmax shift-invariant) with log2(e)/32
// folded into W_qkv's Q-columns so softmax = raw v_exp_f32 (exp2).
// GEMMs: m97 tile (128^2, BK=32, global_load_lds w=16) with 3-buffer
// counted-vmcnt rotation (T4): stage 2 tiles ahead, vmcnt(4) + raw s_barrier
// per K-step, no vmcnt(0) drain in the main loop. Scalar-store epilogue
// (r17's LDS-bounce packing measured +7.6us: stores are NOT critical-path).
// Attention: same T4 pattern; 32x32x16 MFMA, swapped QK^T, P in registers
// (permlane32_swap), 64 q/wave (2 q-sets), 4 waves/block.
// ---------------------------------------------------------------------------

typedef __bf16 bf16x8 __attribute__((ext_vector_type(8)));
typedef __bf16 bf16x4 __attribute__((ext_vector_type(4)));
typedef __bf16 bf16x2 __attribute__((ext_vector_type(2)));
typedef float f32x4 __attribute__((ext_vector_type(4)));
typedef float f32x2 __attribute__((ext_vector_type(2)));
typedef float f32x16 __attribute__((ext_vector_type(16)));
typedef unsigned short ushort8 __attribute__((ext_vector_type(8)));

#define MFMA16(a, b, c) __builtin_amdgcn_mfma_f32_16x16x32_bf16((a), (b), (c), 0, 0, 0)
#define MFMA32(a, b, c) __builtin_amdgcn_mfma_f32_32x32x16_bf16((a), (b), (c), 0, 0, 0)

__device__ __forceinline__ unsigned short f2bf(float f) {
  unsigned int u = __float_as_uint(f);
  u = (u + 0x7FFFu + ((u >> 16) & 1u)) >> 16;  // RNE
  return (unsigned short)u;
}

// Raw v_exp_f32 (exp2). Inputs bounded (|x| <= ~105): no libm guard needed.
__device__ __forceinline__ float fast_exp2(float x) {
#if __has_builtin(__builtin_amdgcn_exp2f)
  return __builtin_amdgcn_exp2f(x);
#else
  float r;
  asm("v_exp_f32 %0, %1" : "=v"(r) : "v"(x));
  return r;
#endif
}

// async global->LDS, 16B per lane. lds dest: wave-uniform base, HW adds lane*16.
__device__ __forceinline__ void gload_lds16(const unsigned short* g, unsigned short* l) {
  __builtin_amdgcn_global_load_lds(
      (const __attribute__((address_space(1))) unsigned int*)g,
      (__attribute__((address_space(3))) unsigned int*)l, 16, 0, 0);
}

// Exchange lane-halves: x[lane<32]=a, x[lane>=32]=b@(lane-32);
//                       y[lane<32]=a@(lane+32), y[lane>=32]=b.
__device__ __forceinline__ void half_swap(unsigned int a, unsigned int b,
                                          unsigned int& x, unsigned int& y,
                                          bool H) {
#if __has_builtin(__builtin_amdgcn_permlane32_swap)
  auto r = __builtin_amdgcn_permlane32_swap(a, b, false, false);
  x = (unsigned int)r[0];
  y = (unsigned int)r[1];
#else
  unsigned int oa = (unsigned int)__shfl_xor((int)a, 32);
  unsigned int ob = (unsigned int)__shfl_xor((int)b, 32);
  x = H ? ob : a;
  y = H ? b : oa;
#endif
}

// ---------------------------------------------------------------------------
// Fused prep: blocks [0,4096): x f32->bf16 (8/thread, 16B stores)
//             blocks [4096,7168): transpose w_qkv -> WqkvT (Q cols pre-scaled)
//             blocks [7168,8192): transpose w_out -> WoutT
// ---------------------------------------------------------------------------
__global__ __launch_bounds__(256) void prep_kernel(
    const float* __restrict__ x, unsigned short* __restrict__ xb,
    const float* __restrict__ wqkv, unsigned short* __restrict__ WqkvT,
    const float* __restrict__ wout, unsigned short* __restrict__ WoutT) {
  const int bid = blockIdx.x;
  const int tid = threadIdx.x;
  if (bid < 4096) {
    int i = (bid * 256 + tid) * 8;
    float4 a = *(const float4*)&x[i];
    float4 b = *(const float4*)&x[i + 4];
    ushort8 o = {f2bf(a.x), f2bf(a.y), f2bf(a.z), f2bf(a.w),
                 f2bf(b.x), f2bf(b.y), f2bf(b.z), f2bf(b.w)};
    *(ushort8*)&xb[i] = o;
    return;
  }
  __shared__ float t[32][33];
  const float* in;
  unsigned short* out;
  int C, scale_limit, c0, r0;
  if (bid < 4096 + 3072) {
    int tj = bid - 4096;
    in = wqkv; out = WqkvT; C = 3072; scale_limit = 1024;
    c0 = (tj % 96) * 32; r0 = (tj / 96) * 32;
  } else {
    int tj = bid - 7168;
    in = wout; out = WoutT; C = 1024; scale_limit = 0;
    c0 = (tj & 31) * 32; r0 = (tj >> 5) * 32;
  }
  const float kQScale = 0.045084220027780106f;  // log2(e) / 32
#pragma unroll
  for (int i = 0; i < 4; ++i) {
    int e = tid + i * 256;
    int r = e >> 5, c = e & 31;
    t[r][c] = in[(size_t)(r0 + r) * C + c0 + c];
  }
  __syncthreads();
#pragma unroll
  for (int i = 0; i < 4; ++i) {
    int e = tid + i * 256;
    int r = e >> 5, c = e & 31;
    float v = t[c][r];
    if (c0 + r < scale_limit) v *= kQScale;
    out[(size_t)(c0 + r) * 1024 + r0 + c] = f2bf(v);
  }
}

// ---------------------------------------------------------------------------
// GEMM: C[M][N] = A[M][K] * Bt[N][K]^T (bf16 in, fp32 accum). 128x128 tile,
// BK=32, linear LDS, global_load_lds w=16, 3-buffer counted-vmcnt rotation:
//   prologue STAGE(0),STAGE(1); per step: vmcnt(4) -> raw s_barrier ->
//   STAGE(j+2) over tile j-1's buffer -> ds_read frags -> 16 MFMA.
// Loads for tile j+1 stay in flight ACROSS the barrier (no drain in loop).
// Safe: only LDS writer is gload_lds (vmcnt-tracked); barrier orders reuse.
// MODE 0: bf16 C. MODE 1: f32 C. MODE 2 (QKV): V-third scattered to VT.
// ---------------------------------------------------------------------------
template <int MODE>
__global__ __launch_bounds__(256) void gemm_bt(
    const unsigned short* __restrict__ A, const unsigned short* __restrict__ Bt,
    void* __restrict__ Cv, unsigned short* __restrict__ VT,
    int M, int N, int K) {
  __shared__ unsigned short As[3 * 4096];  // [buf][128 rows][32 cols]
  __shared__ unsigned short Bs[3 * 4096];
  const int tid = threadIdx.x;
  const int wave = tid >> 6, lane = tid & 63;
  const int g = lane >> 4, ln = lane & 15;
  const int wm = wave >> 1, wn = wave & 1;
  const long bm = (long)blockIdx.y * 128;
  const long bn = (long)blockIdx.x * 128;

  f32x4 acc[4][4];
#pragma unroll
  for (int i = 0; i < 4; ++i)
#pragma unroll
    for (int j = 0; j < 4; ++j) acc[i][j] = (f32x4){0.f, 0.f, 0.f, 0.f};

  const int srow = wave * 32 + (lane >> 2);
  const int scol = (lane & 3) * 8;
  const unsigned short* gA0 = A + (bm + srow) * (long)K + scol;
  const unsigned short* gA1 = gA0 + 16 * (long)K;
  const unsigned short* gB0 = Bt + (bn + srow) * (long)K + scol;
  const unsigned short* gB1 = gB0 + 16 * (long)K;

  auto STAGE = [&](int buf, int k0) {
    unsigned short* lA = &As[buf * 4096 + wave * 1024];
    unsigned short* lB = &Bs[buf * 4096 + wave * 1024];
    gload_lds16(gA0 + k0, lA);
    gload_lds16(gA1 + k0, lA + 512);
    gload_lds16(gB0 + k0, lB);
    gload_lds16(gB1 + k0, lB + 512);
  };

  STAGE(0, 0);
  STAGE(1, 32);

  int bidx = 0;
  for (int k0 = 0; k0 < K; k0 += 32) {
    if (k0 + 32 < K)
      asm volatile("s_waitcnt vmcnt(4)" ::: "memory");
    else
      asm volatile("s_waitcnt vmcnt(0)" ::: "memory");
    __builtin_amdgcn_s_barrier();       // raw: tile j+1 loads stay in flight
    __builtin_amdgcn_sched_barrier(0);  // no hoisting above the barrier
    if (k0 + 64 < K) {
      int nb = bidx + 2; if (nb >= 3) nb -= 3;
      STAGE(nb, k0 + 64);               // overwrites tile j-1's buffer (safe)
    }

    bf16x8 af[4], bfr[4];
#pragma unroll
    for (int i = 0; i < 4; ++i) {
      af[i]  = *(const bf16x8*)&As[bidx * 4096 + (wm * 64 + i * 16 + ln) * 32 + g * 8];
      bfr[i] = *(const bf16x8*)&Bs[bidx * 4096 + (wn * 64 + i * 16 + ln) * 32 + g * 8];
    }
    __builtin_amdgcn_s_setprio(1);
#pragma unroll
    for (int i = 0; i < 4; ++i)
#pragma unroll
      for (int j = 0; j < 4; ++j)
        acc[i][j] = MFMA16(af[i], bfr[j], acc[i][j]);
    __builtin_amdgcn_s_setprio(0);

    bidx = (bidx == 2) ? 0 : bidx + 1;
  }

  const long crow = bm + wm * 64, ccol = bn + wn * 64;
  if (MODE == 2 && bn >= 2048) {
    // V block: write VT[bh][dh][t] only (qkv's V third is never read).
#pragma unroll
    for (int i = 0; i < 4; ++i)
#pragma unroll
      for (int j = 0; j < 4; ++j) {
        int nv = (int)(ccol + j * 16 + ln) - 2048;  // 0..1023
        int h = nv >> 6, dh = nv & 63;
        long tg = crow + i * 16 + g * 4;            // t of acc[..][0]
        int b = (int)(tg >> 11), tl = (int)(tg & 2047);
        size_t idx = (size_t)(b * 16 + h) * 131072 + (size_t)dh * 2048 + tl;
        bf16x4 o = {(__bf16)acc[i][j][0], (__bf16)acc[i][j][1],
                    (__bf16)acc[i][j][2], (__bf16)acc[i][j][3]};
        *(bf16x4*)&VT[idx] = o;
      }
  } else {
#pragma unroll
    for (int i = 0; i < 4; ++i)
#pragma unroll
      for (int j = 0; j < 4; ++j)
#pragma unroll
        for (int r = 0; r < 4; ++r) {
          long idx = (crow + i * 16 + g * 4 + r) * (long)N + ccol + j * 16 + ln;
          if (MODE == 1)
            ((float*)Cv)[idx] = acc[i][j][r];
          else
            ((unsigned short*)Cv)[idx] = f2bf(acc[i][j][r]);
        }
  }
}

// ---------------------------------------------------------------------------
// Flash attention, 32x32x16 MFMA, swapped-operand, max-free softmax, P in regs.
// Block = one (b,h) x 256 q-rows; 4 waves x 64 q each (two 32-q sets A,B).
// 3-buffer K/V rotation, staged 2 tiles ahead; per tile:
//   s_waitcnt vmcnt(4) -> raw s_barrier -> STAGE(j+2) -> compute tile j.
// No ds_writes exist (P in regs) -> raw barrier needs no lgkm drain.
// ---------------------------------------------------------------------------
__global__ __launch_bounds__(256, 2) void attn_kernel(
    const unsigned short* __restrict__ qkv, const unsigned short* __restrict__ VT,
    unsigned short* __restrict__ attn_out) {
  __shared__ unsigned short Ks[3][64][64];  // [buf][key][dh], swizzled content
  __shared__ unsigned short Vs[3][64][64];  // [buf][dh][key], swizzled content

  const int tid = threadIdx.x;
  const int wave = tid >> 6, lane = tid & 63;
  const int l31 = lane & 31, hb = lane >> 5;

  // XCD-chunked bijective swizzle: each XCD owns 64 consecutive wg = 8 bh
  // (K/V working set 8*512KB = 4MB = L2-resident).
  const int wg = (blockIdx.x & 7) * 64 + (blockIdx.x >> 3);
  const int bh = wg >> 3, qc = wg & 7;
  const int b = bh >> 4, head = bh & 15;
  const int q0 = qc * 256 + wave * 64;  // this wave's 64 q-rows (A: +0, B: +32)

  // Q B-frags, two sets: qf*[t]: n=q, k(dh) = 16t + 8hb + i. W_q pre-scaled.
  bf16x8 qfA[4], qfB[4];
  {
    size_t baseA = (size_t)(b * 2048 + q0 + l31) * 3072 + head * 64 + 8 * hb;
    size_t baseB = baseA + (size_t)32 * 3072;
    qfA[0] = *(const bf16x8*)&qkv[baseA];
    qfA[1] = *(const bf16x8*)&qkv[baseA + 16];
    qfA[2] = *(const bf16x8*)&qkv[baseA + 32];
    qfA[3] = *(const bf16x8*)&qkv[baseA + 48];
    qfB[0] = *(const bf16x8*)&qkv[baseB];
    qfB[1] = *(const bf16x8*)&qkv[baseB + 16];
    qfB[2] = *(const bf16x8*)&qkv[baseB + 32];
    qfB[3] = *(const bf16x8*)&qkv[baseB + 48];
  }

  f32x16 oaccA[2], oaccB[2];
#pragma unroll
  for (int i = 0; i < 16; ++i) {
    oaccA[0][i] = 0.f; oaccA[1][i] = 0.f;
    oaccB[0][i] = 0.f; oaccB[1][i] = 0.f;
  }
  f32x2 lsA = {0.f, 0.f}, lsB = {0.f, 0.f};

  // Staging: LDS linear (gload_lds HW layout); global SOURCE pre-swizzled
  // (chunk sc ^ (srow&7)) so reading LDS[row][c ^ (row&7)] = logical col c.
  const int srow = tid >> 3;                     // 0..31
  const int sc = tid & 7;
  const int swz = (sc ^ (srow & 7)) * 8;         // swizzled chunk (elems)
  const unsigned short* gK =
      qkv + (size_t)b * 2048 * 3072 + 1024 + head * 64 + (size_t)srow * 3072 + swz;
  const unsigned short* gV = VT + (size_t)bh * 131072 + (size_t)srow * 2048 + swz;
  const int wrow = wave * 8;  // wave-uniform LDS row base for staging

  auto STAGE = [&](int buf, int j) {
    gload_lds16(gK + (size_t)j * 3072,        &Ks[buf][wrow][0]);
    gload_lds16(gK + (size_t)(j + 32) * 3072, &Ks[buf][wrow + 32][0]);
    gload_lds16(gV + j,                       &Vs[buf][wrow][0]);
    gload_lds16(gV + 32 * 2048 + j,           &Vs[buf][wrow + 32][0]);
  };

  const int myx = l31 & 7;  // XOR key for frag reads
  const bool H = (hb != 0);

  // prologue: stage tiles 0 and 1 into bufs 0 and 1
  STAGE(0, 0);
  STAGE(1, 64);

  int idx = 0;
  for (int j0 = 0; j0 < 2048; j0 += 64) {
    // Tile j resident when all but the newest 4 loads (tile j+1) are done.
    if (j0 + 64 < 2048)
      asm volatile("s_waitcnt vmcnt(4)" ::: "memory");
    else
      asm volatile("s_waitcnt vmcnt(0)" ::: "memory");
    __builtin_amdgcn_s_barrier();      // raw: loads for j+1 stay in flight
    __builtin_amdgcn_sched_barrier(0); // pin: no hoisting above the barrier
    if (j0 + 128 < 2048) {
      int nb = idx + 2; if (nb >= 3) nb -= 3;
      STAGE(nb, j0 + 128);             // overwrites tile j-1's buffer (safe)
    }

#pragma unroll
    for (int kt = 0; kt < 2; ++kt) {
      // S^T over 32 keys (this kt) x 64 q: one kf read feeds both q-sets.
      f32x16 saA, saB;
#pragma unroll
      for (int i = 0; i < 16; ++i) { saA[i] = 0.f; saB[i] = 0.f; }
      __builtin_amdgcn_s_setprio(1);
#pragma unroll
      for (int t = 0; t < 4; ++t) {
        bf16x8 kf = *(const bf16x8*)&Ks[idx][kt * 32 + l31][((2 * t + hb) ^ myx) * 8];
        saA = MFMA32(kf, qfA[t], saA);
        saB = MFMA32(kf, qfB[t], saB);
      }
      __builtin_amdgcn_s_setprio(0);

      // P = exp2(S); pack reg-pairs to bf16x2; lane-local pk_add lsum.
      unsigned int pkwA[8], pkwB[8];
#pragma unroll
      for (int j = 0; j < 8; ++j) {
        float a0 = fast_exp2(saA[2 * j]);
        float a1 = fast_exp2(saA[2 * j + 1]);
        lsA += (f32x2){a0, a1};
        bf16x2 av = {(__bf16)a0, (__bf16)a1};
        pkwA[j] = __builtin_bit_cast(unsigned int, av);
        float b0 = fast_exp2(saB[2 * j]);
        float b1 = fast_exp2(saB[2 * j + 1]);
        lsB += (f32x2){b0, b1};
        bf16x2 bv = {(__bf16)b0, (__bf16)b1};
        pkwB[j] = __builtin_bit_cast(unsigned int, bv);
      }

      // Reassemble PV B-frags via lane-half swaps (element i -> key 16s+8hb+i).
      union { unsigned int u[4]; bf16x8 v; } pfA0, pfA1, pfB0, pfB1;
      half_swap(pkwA[0], pkwA[2], pfA0.u[0], pfA0.u[2], H);
      half_swap(pkwA[1], pkwA[3], pfA0.u[1], pfA0.u[3], H);
      half_swap(pkwA[4], pkwA[6], pfA1.u[0], pfA1.u[2], H);
      half_swap(pkwA[5], pkwA[7], pfA1.u[1], pfA1.u[3], H);
      half_swap(pkwB[0], pkwB[2], pfB0.u[0], pfB0.u[2], H);
      half_swap(pkwB[1], pkwB[3], pfB0.u[1], pfB0.u[3], H);
      half_swap(pkwB[4], pkwB[6], pfB1.u[0], pfB1.u[2], H);
      half_swap(pkwB[5], pkwB[7], pfB1.u[1], pfB1.u[3], H);

      // O^T += V^T * P^T: one vf pair read feeds both q-sets.
      __builtin_amdgcn_s_setprio(1);
#pragma unroll
      for (int mt = 0; mt < 2; ++mt) {
        bf16x8 vf0 = *(const bf16x8*)&Vs[idx][mt * 32 + l31][((4 * kt + hb) ^ myx) * 8];
        bf16x8 vf1 = *(const bf16x8*)&Vs[idx][mt * 32 + l31][((4 * kt + 2 + hb) ^ myx) * 8];
        oaccA[mt] = MFMA32(vf0, pfA0.v, oaccA[mt]);
        oaccA[mt] = MFMA32(vf1, pfA1.v, oaccA[mt]);
        oaccB[mt] = MFMA32(vf0, pfB0.v, oaccB[mt]);
        oaccB[mt] = MFMA32(vf1, pfB1.v, oaccB[mt]);
      }
      __builtin_amdgcn_s_setprio(0);
    }

    idx = (idx == 2) ? 0 : idx + 1;
  }

  // Epilogue per set: halves hold disjoint key sets for the same q.
  {
    float l = lsA.x + lsA.y;
    l += __shfl_xor(l, 32);
    float inv = 1.0f / l;
    size_t row = (size_t)(b * 2048 + q0 + l31) * 1024 + head * 64;
#pragma unroll
    for (int mt = 0; mt < 2; ++mt)
#pragma unroll
      for (int rq = 0; rq < 4; ++rq) {
        bf16x4 o = {(__bf16)(oaccA[mt][4 * rq + 0] * inv),
                    (__bf16)(oaccA[mt][4 * rq + 1] * inv),
                    (__bf16)(oaccA[mt][4 * rq + 2] * inv),
                    (__bf16)(oaccA[mt][4 * rq + 3] * inv)};
        *(bf16x4*)&attn_out[row + mt * 32 + 8 * rq + 4 * hb] = o;
      }
  }
  {
    float l = lsB.x + lsB.y;
    l += __shfl_xor(l, 32);
    float inv = 1.0f / l;
    size_t row = (size_t)(b * 2048 + q0 + 32 + l31) * 1024 + head * 64;
#pragma unroll
    for (int mt = 0; mt < 2; ++mt)
#pragma unroll
      for (int rq = 0; rq < 4; ++rq) {
        bf16x4 o = {(__bf16)(oaccB[mt][4 * rq + 0] * inv),
                    (__bf16)(oaccB[mt][4 * rq + 1] * inv),
                    (__bf16)(oaccB[mt][4 * rq + 2] * inv),
                    (__bf16)(oaccB[mt][4 * rq + 3] * inv)};
        *(bf16x4*)&attn_out[row + mt * 32 + 8 * rq + 4 * hb] = o;
      }
  }
}

// ---------------------------------------------------------------------------
extern "C" void kernel_launch(void* const* d_in, const int* in_sizes, int n_in,
                              void* d_out, int out_size, void* d_ws, size_t ws_size,
                              hipStream_t stream) {
  (void)in_sizes; (void)n_in; (void)out_size; (void)ws_size;
  const float* x_f     = (const float*)d_in[0];
  const float* w_qkv_f = (const float*)d_in[1];
  const float* w_out_f = (const float*)d_in[2];
  float* out = (float*)d_out;

  char* ws = (char*)d_ws;
  unsigned short* qkv   = (unsigned short*)(ws);                 // 50331648 B
  unsigned short* attn  = (unsigned short*)(ws + 50331648);      // 16777216 B
  unsigned short* VT    = (unsigned short*)(ws + 67108864);      // 16777216 B
  unsigned short* WqkvT = (unsigned short*)(ws + 83886080);      // 6291456 B
  unsigned short* WoutT = (unsigned short*)(ws + 90177536);      // 2097152 B
  unsigned short* xb    = (unsigned short*)(ws + 92274688);      // 16777216 B

  prep_kernel<<<8192, 256, 0, stream>>>(x_f, xb, w_qkv_f, WqkvT, w_out_f, WoutT);
  gemm_bt<2><<<dim3(24, 64), 256, 0, stream>>>(xb, WqkvT, qkv, VT, 8192, 3072, 1024);
  attn_kernel<<<512, 256, 0, stream>>>(qkv, VT, attn);
  gemm_bt<1><<<dim3(8, 64), 256, 0, stream>>>(attn, WoutT, out, nullptr, 8192, 1024, 1024);
}